// Round 5
// baseline (299.954 us; speedup 1.0000x reference)
//
#include <hip/hip_runtime.h>

#define HIDDEN 768
#define VOCAB  32000
#define HS1    128
#define NSTAGE 24          // 24 stages x 32 k (one MFMA K-step per stage)
#define LSTRIDE 36         // floats per LDS row (144 B; 36 % 32 == 4 -> conflict-free b128 phases)

typedef __attribute__((ext_vector_type(8))) short bf16x8;
typedef __attribute__((ext_vector_type(4))) float f32x4;

// fp32 -> bf16 bits, round-to-nearest-even
__device__ __forceinline__ unsigned short f2bf(float f) {
    union { float f; unsigned u; } x; x.f = f;
    unsigned r = x.u + 0x7fffu + ((x.u >> 16) & 1u);
    return (unsigned short)(r >> 16);
}

// Pack W1[VOCAB:VOCAB+768, 0:128] into bf16 MFMA B-fragment order.
// Coalesced contiguous READ of W1, scattered 2-B writes (fire-and-forget).
// Bp[((ks*8+nt)*64+lane)*8+j] = B[k=ks*32+(lane>>4)*8+j][n=nt*16+(lane&15)].
__global__ void pack_b_kernel(const float* __restrict__ W1,
                              unsigned short* __restrict__ Bp) {
    int tid = blockIdx.x * 256 + threadIdx.x;   // 0 .. 98303
    float v = W1[(size_t)VOCAB * HS1 + tid];
    int k = tid >> 7;                            // 0..767
    int n = tid & 127;
    int ks = k >> 5, kr = k & 31;
    int quad = kr >> 3, j = kr & 7;
    int nt = n >> 4, c = n & 15;
    int lane = quad * 16 + c;
    Bp[(((ks * 8 + nt) * 64 + lane) << 3) + j] = f2bf(v);
}

// Persistent: each block processes 2 tiles of 128 rows (grid = 256).
// One wave = 32 token rows (2 m-tiles) x N=128 (8 n-tiles), K=768.
// hs0 staged via wave-private double-buffered LDS (coalesced 128-B/8-lane
// global loads, nontemporal); A-fragments via conflict-free ds_read_b128;
// B pre-packed bf16 (L2-hot). No barriers (per-wave in-order LDS w->r).
// Tile 1's first stage-load is issued before tile 0's epilogue to hide
// the ~900-cyc cold-load latency behind the gather/reduce.
__launch_bounds__(256, 2)
__global__ void classifier_kernel(const int* __restrict__ tk,
                                  const float* __restrict__ hs0,
                                  const float* __restrict__ W1,
                                  const float* __restrict__ b1,
                                  const float* __restrict__ W2,
                                  const float* __restrict__ b2,
                                  const unsigned short* __restrict__ Bp,
                                  float* __restrict__ out) {
    __shared__ float lds[4][2][32 * LSTRIDE];   // 36864 B / block

    const int lane = threadIdx.x & 63;
    const int wave = threadIdx.x >> 6;      // 0..3
    const int quad = lane >> 4;             // 0..3
    const int col  = lane & 15;             // 0..15

    float* buf0 = &lds[wave][0][0];
    float* buf1 = &lds[wave][1][0];

    // Staging mapping: instr i (0..3), lane l -> row = i*8 + (l>>3),
    // float offset (l&7)*4. 8 consecutive lanes cover one row's 128-B slab.
    const int srow = lane >> 3;             // 0..7
    const int scol = (lane & 7) * 4;        // 0,4,..,28

    f32x4 greg[4];
    const float* gb;                        // current tile's hs0 base
    auto gload = [&](int s) {
#pragma unroll
        for (int i = 0; i < 4; ++i) {
            const float* p = gb + (size_t)(i * 8 + srow) * HIDDEN + s * 32 + scol;
            greg[i] = __builtin_nontemporal_load((const f32x4*)p);
        }
    };
    auto lstore = [&](float* buf) {
#pragma unroll
        for (int i = 0; i < 4; ++i)
            *(f32x4*)(buf + (i * 8 + srow) * LSTRIDE + scol) = greg[i];
    };

    const unsigned short* pb0 = Bp + lane * 8;
    auto loadB = [&](int kstep, bf16x8* b) {
        const unsigned short* pb = pb0 + kstep * 4096;
#pragma unroll
        for (int nt = 0; nt < 4; ++nt) {
            b[nt]     = *(const bf16x8*)(pb + nt * 512);
            b[nt + 4] = *(const bf16x8*)(pb + 2048 + nt * 512);
        }
    };

    auto cvt8 = [&](f32x4 lo, f32x4 hi) {
        bf16x8 r;
        r[0] = (short)f2bf(lo[0]); r[1] = (short)f2bf(lo[1]);
        r[2] = (short)f2bf(lo[2]); r[3] = (short)f2bf(lo[3]);
        r[4] = (short)f2bf(hi[0]); r[5] = (short)f2bf(hi[1]);
        r[6] = (short)f2bf(hi[2]); r[7] = (short)f2bf(hi[3]);
        return r;
    };

    f32x4 acc[2][8];
    auto stage_body = [&](int s, float* cur, float* alt,
                          const bf16x8* bc, bf16x8* bn) {
        if (s + 1 < NSTAGE) loadB(s + 1, bn);
        if (s + 1 < NSTAGE) lstore(alt);       // greg holds stage s+1
        if (s + 2 < NSTAGE) gload(s + 2);
        // A fragments: lane -> A[m=col][k=quad*8+j], m-tile 1 at +16 rows.
        const float* p0 = cur + col * LSTRIDE + quad * 8;
        const float* p1 = p0 + 16 * LSTRIDE;
        f32x4 a0l = *(const f32x4*)p0, a0h = *(const f32x4*)(p0 + 4);
        f32x4 a1l = *(const f32x4*)p1, a1h = *(const f32x4*)(p1 + 4);
        bf16x8 af0 = cvt8(a0l, a0h);
        bf16x8 af1 = cvt8(a1l, a1h);
#pragma unroll
        for (int nt = 0; nt < 8; ++nt) {
            acc[0][nt] = __builtin_amdgcn_mfma_f32_16x16x32_bf16(af0, bc[nt], acc[0][nt], 0, 0, 0);
            acc[1][nt] = __builtin_amdgcn_mfma_f32_16x16x32_bf16(af1, bc[nt], acc[1][nt], 0, 0, 0);
        }
    };

    // Tile-invariant epilogue vectors (hoisted out of the tile loop).
    const float bb2 = b2[0];
    float b1v[8], w2v[8];
#pragma unroll
    for (int nt = 0; nt < 8; ++nt) {
        b1v[nt] = b1[nt * 16 + col];
        w2v[nt] = W2[nt * 16 + col];
    }

    bf16x8 bfrA[8], bfrB[8];   // NOT b0/b1: parameter-name collision (R3)

    // Prefetch tile 0 stage 0.
    int row0 = (blockIdx.x * 4 + wave) * 32;
    gb = hs0 + (size_t)row0 * HIDDEN;
    gload(0);

#pragma unroll 1
    for (int t = 0; t < 2; ++t) {
        // Token ids for this tile's epilogue (overlap with K-loop).
        int toks[8];
#pragma unroll
        for (int mt = 0; mt < 2; ++mt)
#pragma unroll
            for (int reg = 0; reg < 4; ++reg)
                toks[mt * 4 + reg] = tk[row0 + mt * 16 + quad * 4 + reg];

#pragma unroll
        for (int mt = 0; mt < 2; ++mt)
#pragma unroll
            for (int nt = 0; nt < 8; ++nt)
                acc[mt][nt] = (f32x4){0.f, 0.f, 0.f, 0.f};

        // Prologue: greg holds this tile's stage 0.
        lstore(buf0);
        gload(1);
        loadB(0, bfrA);

#pragma unroll 1
        for (int s = 0; s < NSTAGE; s += 2) {
            stage_body(s,     buf0, buf1, bfrA, bfrB);
            stage_body(s + 1, buf1, buf0, bfrB, bfrA);
        }

        // Prefetch next tile's stage 0 before this tile's epilogue.
        int row_next = row0 + gridDim.x * 128;
        if (t == 0) {
            gb = hs0 + (size_t)row_next * HIDDEN;
            gload(0);
        }

        // Epilogue: h = relu(acc + W1[tok] + b1); out = h . W2 + b2
        // C/D layout: n = nt*16 + col, row-in-tile = quad*4 + reg.
#pragma unroll
        for (int mt = 0; mt < 2; ++mt) {
#pragma unroll
            for (int reg = 0; reg < 4; ++reg) {
                int r = row0 + mt * 16 + quad * 4 + reg;
                const float* wrow = W1 + (size_t)toks[mt * 4 + reg] * HS1;
                float p = 0.f;
#pragma unroll
                for (int nt = 0; nt < 8; ++nt) {
                    float v = acc[mt][nt][reg] + wrow[nt * 16 + col] + b1v[nt];
                    v = fmaxf(v, 0.f);
                    p = fmaf(v, w2v[nt], p);
                }
                p += __shfl_xor(p, 1);
                p += __shfl_xor(p, 2);
                p += __shfl_xor(p, 4);
                p += __shfl_xor(p, 8);
                if (col == 0) out[r] = p + bb2;
            }
        }
        row0 = row_next;
    }
}

extern "C" void kernel_launch(void* const* d_in, const int* in_sizes, int n_in,
                              void* d_out, int out_size, void* d_ws, size_t ws_size,
                              hipStream_t stream) {
    const int*   tk  = (const int*)d_in[0];
    const float* hs0 = (const float*)d_in[1];
    const float* W1  = (const float*)d_in[2];
    const float* b1  = (const float*)d_in[3];
    const float* W2  = (const float*)d_in[4];
    const float* b2  = (const float*)d_in[5];
    float* out = (float*)d_out;
    unsigned short* Bp = (unsigned short*)d_ws;   // 768*128*2 = 196608 B

    pack_b_kernel<<<(HIDDEN * HS1) / 256, 256, 0, stream>>>(W1, Bp);

    int n_tokens = in_sizes[0];        // 16*4096 = 65536
    int grid = n_tokens / 256;         // 256 blocks x 2 tiles x 128 rows
    classifier_kernel<<<grid, 256, 0, stream>>>(tk, hs0, W1, b1, W2, b2, Bp, out);
}

// Round 6
// 290.697 us; speedup vs baseline: 1.0318x; 1.0318x over previous
//
#include <hip/hip_runtime.h>

#define HIDDEN 768
#define VOCAB  32000
#define HS1    128
#define NSTAGE 24          // 24 stages x 32 k (one MFMA K-step per stage)
#define LSTRIDE 36         // floats per LDS row (144 B; 36 % 32 == 4 -> conflict-free b128 phases)

typedef __attribute__((ext_vector_type(8))) short bf16x8;
typedef __attribute__((ext_vector_type(4))) float f32x4;

// fp32 -> bf16 bits, round-to-nearest-even
__device__ __forceinline__ unsigned short f2bf(float f) {
    union { float f; unsigned u; } x; x.f = f;
    unsigned r = x.u + 0x7fffu + ((x.u >> 16) & 1u);
    return (unsigned short)(r >> 16);
}

// Pack W1[VOCAB:VOCAB+768, 0:128] into bf16 MFMA B-fragment order.
// Coalesced contiguous READ of W1, scattered 2-B writes (fire-and-forget).
// Bp[((ks*8+nt)*64+lane)*8+j] = B[k=ks*32+(lane>>4)*8+j][n=nt*16+(lane&15)].
__global__ void pack_b_kernel(const float* __restrict__ W1,
                              unsigned short* __restrict__ Bp) {
    int tid = blockIdx.x * 256 + threadIdx.x;   // 0 .. 98303
    float v = W1[(size_t)VOCAB * HS1 + tid];
    int k = tid >> 7;                            // 0..767
    int n = tid & 127;
    int ks = k >> 5, kr = k & 31;
    int quad = kr >> 3, j = kr & 7;
    int nt = n >> 4, c = n & 15;
    int lane = quad * 16 + c;
    Bp[(((ks * 8 + nt) * 64 + lane) << 3) + j] = f2bf(v);
}

// One wave = 32 token rows (2 m-tiles) x N=128 (8 n-tiles), K=768.
// grid=512 (2 blocks/CU — R5 showed 1 block/CU de-saturates HBM: TLP
// in-flight bytes drop below the ~23 KB/CU latency-BW product).
// hs0 staged via wave-private double-buffered LDS with coalesced 128-B/8-lane
// nontemporal loads; staging registers are ALSO double-buffered (gA/gB) so
// each wave keeps TWO stages (8 KB) of HBM loads in flight -> 64 KB/CU.
// A-fragments via conflict-free ds_read_b128; B pre-packed bf16 (L2-hot).
// No barriers (wave-private tiles; per-wave in-order LDS w->r).
__launch_bounds__(256, 2)
__global__ void classifier_kernel(const int* __restrict__ tk,
                                  const float* __restrict__ hs0,
                                  const float* __restrict__ W1,
                                  const float* __restrict__ b1,
                                  const float* __restrict__ W2,
                                  const float* __restrict__ b2,
                                  const unsigned short* __restrict__ Bp,
                                  float* __restrict__ out) {
    __shared__ float lds[4][2][32 * LSTRIDE];   // 36864 B / block

    const int lane = threadIdx.x & 63;
    const int wave = threadIdx.x >> 6;      // 0..3
    const int quad = lane >> 4;             // 0..3
    const int col  = lane & 15;             // 0..15
    const int row0 = (blockIdx.x * 4 + wave) * 32;

    float* buf0 = &lds[wave][0][0];
    float* buf1 = &lds[wave][1][0];

    // Staging mapping: instr i (0..3), lane l -> row = i*8 + (l>>3),
    // float offset (l&7)*4. 8 consecutive lanes cover one row's 128-B slab.
    const int srow = lane >> 3;             // 0..7
    const int scol = (lane & 7) * 4;        // 0,4,..,28
    const float* gbase = hs0 + (size_t)row0 * HIDDEN;

    // Prefetch the 8 token ids this lane's epilogue needs.
    int toks[8];
#pragma unroll
    for (int mt = 0; mt < 2; ++mt)
#pragma unroll
        for (int reg = 0; reg < 4; ++reg)
            toks[mt * 4 + reg] = tk[row0 + mt * 16 + quad * 4 + reg];

    f32x4 acc[2][8];
#pragma unroll
    for (int mt = 0; mt < 2; ++mt)
#pragma unroll
        for (int nt = 0; nt < 8; ++nt)
            acc[mt][nt] = (f32x4){0.f, 0.f, 0.f, 0.f};

    // Two staging register buffers -> two gload stages in flight per wave.
    f32x4 gA[4], gB[4];
    auto gload = [&](f32x4* g, int s) {
#pragma unroll
        for (int i = 0; i < 4; ++i) {
            const float* p = gbase + (size_t)(i * 8 + srow) * HIDDEN + s * 32 + scol;
            g[i] = __builtin_nontemporal_load((const f32x4*)p);
        }
    };
    auto lstore = [&](float* buf, const f32x4* g) {
#pragma unroll
        for (int i = 0; i < 4; ++i)
            *(f32x4*)(buf + (i * 8 + srow) * LSTRIDE + scol) = g[i];
    };

    const unsigned short* pb0 = Bp + lane * 8;
    auto loadB = [&](int kstep, bf16x8* b) {
        const unsigned short* pb = pb0 + kstep * 4096;
#pragma unroll
        for (int nt = 0; nt < 4; ++nt) {
            b[nt]     = *(const bf16x8*)(pb + nt * 512);
            b[nt + 4] = *(const bf16x8*)(pb + 2048 + nt * 512);
        }
    };

    auto cvt8 = [&](f32x4 lo, f32x4 hi) {
        bf16x8 r;
        r[0] = (short)f2bf(lo[0]); r[1] = (short)f2bf(lo[1]);
        r[2] = (short)f2bf(lo[2]); r[3] = (short)f2bf(lo[3]);
        r[4] = (short)f2bf(hi[0]); r[5] = (short)f2bf(hi[1]);
        r[6] = (short)f2bf(hi[2]); r[7] = (short)f2bf(hi[3]);
        return r;
    };

    // body(s): consume LDS stage s from `cur`; store stage s+1 from `gs`
    // (freeing it), then issue gload of stage s+3 into the SAME buffer.
    // Steady state: stages s+2 and s+3 in flight concurrently.
    auto stage_body = [&](int s, float* cur, float* alt, f32x4* gs,
                          const bf16x8* bc, bf16x8* bn) {
        if (s + 1 < NSTAGE) loadB(s + 1, bn);
        if (s + 1 < NSTAGE) lstore(alt, gs);
        if (s + 3 < NSTAGE) gload(gs, s + 3);
        // A fragments: lane -> A[m=col][k=quad*8+j], m-tile 1 at +16 rows.
        const float* p0 = cur + col * LSTRIDE + quad * 8;
        const float* p1 = p0 + 16 * LSTRIDE;
        f32x4 a0l = *(const f32x4*)p0, a0h = *(const f32x4*)(p0 + 4);
        f32x4 a1l = *(const f32x4*)p1, a1h = *(const f32x4*)(p1 + 4);
        bf16x8 af0 = cvt8(a0l, a0h);
        bf16x8 af1 = cvt8(a1l, a1h);
#pragma unroll
        for (int nt = 0; nt < 8; ++nt) {
            acc[0][nt] = __builtin_amdgcn_mfma_f32_16x16x32_bf16(af0, bc[nt], acc[0][nt], 0, 0, 0);
            acc[1][nt] = __builtin_amdgcn_mfma_f32_16x16x32_bf16(af1, bc[nt], acc[1][nt], 0, 0, 0);
        }
    };

    // Prologue: stage0 -> gA -> buf0; stage1 -> gB (stays in flight);
    // stage2 -> gA. K-step 0 B-fragments in flight.
    // (bfrA/bfrB: NOT b0/b1 — parameter-name collision, R3.)
    bf16x8 bfrA[8], bfrB[8];
    gload(gA, 0);
    gload(gB, 1);
    lstore(buf0, gA);        // waits on gA only; gB remains outstanding
    gload(gA, 2);
    loadB(0, bfrA);

    // Even s: cur=buf0, stage s+1 comes from gB; odd s: cur=buf1, from gA.
#pragma unroll 1
    for (int s = 0; s < NSTAGE; s += 2) {
        stage_body(s,     buf0, buf1, gB, bfrA, bfrB);
        stage_body(s + 1, buf1, buf0, gA, bfrB, bfrA);
    }

    // Epilogue: h = relu(acc + W1[tok] + b1); out = h . W2 + b2
    // C/D layout: n = nt*16 + col, row-in-tile = quad*4 + reg.
    const float bb2 = b2[0];
    float b1v[8], w2v[8];
#pragma unroll
    for (int nt = 0; nt < 8; ++nt) {
        b1v[nt] = b1[nt * 16 + col];
        w2v[nt] = W2[nt * 16 + col];
    }
#pragma unroll
    for (int mt = 0; mt < 2; ++mt) {
#pragma unroll
        for (int reg = 0; reg < 4; ++reg) {
            int r = row0 + mt * 16 + quad * 4 + reg;
            const float* wrow = W1 + (size_t)toks[mt * 4 + reg] * HS1;
            float p = 0.f;
#pragma unroll
            for (int nt = 0; nt < 8; ++nt) {
                float v = acc[mt][nt][reg] + wrow[nt * 16 + col] + b1v[nt];
                v = fmaxf(v, 0.f);
                p = fmaf(v, w2v[nt], p);
            }
            p += __shfl_xor(p, 1);
            p += __shfl_xor(p, 2);
            p += __shfl_xor(p, 4);
            p += __shfl_xor(p, 8);
            if (col == 0) out[r] = p + bb2;
        }
    }
}

extern "C" void kernel_launch(void* const* d_in, const int* in_sizes, int n_in,
                              void* d_out, int out_size, void* d_ws, size_t ws_size,
                              hipStream_t stream) {
    const int*   tk  = (const int*)d_in[0];
    const float* hs0 = (const float*)d_in[1];
    const float* W1  = (const float*)d_in[2];
    const float* b1  = (const float*)d_in[3];
    const float* W2  = (const float*)d_in[4];
    const float* b2  = (const float*)d_in[5];
    float* out = (float*)d_out;
    unsigned short* Bp = (unsigned short*)d_ws;   // 768*128*2 = 196608 B

    pack_b_kernel<<<(HIDDEN * HS1) / 256, 256, 0, stream>>>(W1, Bp);

    int n_tokens = in_sizes[0];        // 16*4096 = 65536
    int grid = n_tokens / 128;         // 512 blocks: 2 blocks/CU (R5 lesson)
    classifier_kernel<<<grid, 256, 0, stream>>>(tk, hs0, W1, b1, W2, b2, Bp, out);
}